// Round 7
// baseline (499.348 us; speedup 1.0000x reference)
//
#include <hip/hip_runtime.h>
#include <math.h>

constexpr int BB  = 32;
constexpr int SQL = 2048;
constexpr int SKL = 2048;
constexpr int DD  = 64;
constexpr int RB  = 64;           // q rows per block
constexpr int CK  = 64;           // cols per chunk
constexpr int NC  = SKL / CK;     // 32 chunks

using f32x4 = __attribute__((ext_vector_type(4))) float;
using bfrag = __attribute__((ext_vector_type(8))) short;   // 8 bf16 = 4 VGPR

static __device__ __forceinline__ unsigned short f2bf(float x) {
    unsigned u = __float_as_uint(x);
    u = u + 0x7FFFu + ((u >> 16) & 1u);          // round-nearest-even
    return (unsigned short)(u >> 16);
}
static __device__ __forceinline__ float bf2f(unsigned short h) {
    return __uint_as_float((unsigned)h << 16);
}

// async global->LDS, 16 B per lane, linear dest (wave-uniform base + lane*16)
static __device__ __forceinline__ void gld16(const void* g, void* l) {
    __builtin_amdgcn_global_load_lds(
        (const __attribute__((address_space(1))) void*)(size_t)g,
        (__attribute__((address_space(3))) void*)(unsigned)(size_t)l,
        16, 0, 0);
}

// ---- prepass: k fp32 -> swizzled bf16 hi/lo records.
// Per (b,c): 256 B = [hi d0..63][lo d0..63]; 16-B groups XOR'd by ((c&7)<<4)
// so the main kernel's ds_read_b128 per-col fragment reads are conflict-free
// while the global->LDS DMA stays perfectly linear.
__global__ __launch_bounds__(256) void split_k_swz(
    const float* __restrict__ k, unsigned char* __restrict__ kswz)
{
    const int i0 = blockIdx.x * blockDim.x + threadIdx.x;  // (b,c,g), exact grid
    const int g  = i0 & 7;
    const int c  = (i0 >> 3) & 2047;
    const int b  = i0 >> 14;
    const float* kp = k + ((size_t)(b * 2048 + c)) * DD + g * 8;
    bfrag h, lo;
    #pragma unroll
    for (int j = 0; j < 8; ++j) {
        const float x = kp[j];
        const unsigned short hh = f2bf(x);
        h[j]  = (short)hh;
        lo[j] = (short)f2bf(x - bf2f(hh));
    }
    const int sw = (c & 7) << 4;
    unsigned char* rec = kswz + ((size_t)(b * 2048 + c)) * 256;
    *(bfrag*)(rec + ((g * 16) ^ sw))       = h;
    *(bfrag*)(rec + 128 + ((g * 16) ^ sw)) = lo;
}

// ---- main: 1024 thr = 16 waves; block owns 64 rows x 2048 cols.
// Per chunk (64 cols): k (16 KB swizzled bf16) + mask (16 KB int32) DMA'd to
// LDS double-buffers; wave w computes sub-tile rows (w&3)*16.., cols (w>>2)*16...
template<bool PRE>
__global__ __launch_bounds__(1024, 4) void sdpa_big(
    const float* __restrict__ q, const float* __restrict__ k,
    const int* __restrict__ mask, const unsigned char* __restrict__ kswz,
    float* __restrict__ out)
{
    __shared__ unsigned char pool[65536];
    unsigned char* kb0 = pool;              // 16 KB
    unsigned char* kb1 = pool + 16384;      // 16 KB
    unsigned char* mb0 = pool + 32768;      // 16 KB
    unsigned char* mb1 = pool + 49152;      // 16 KB
    float* s_red = (float*)pool;            // aliases kb0; used only after loop

    const int t   = threadIdx.x;
    const int l   = t & 63;
    const int w   = t >> 6;
    const int lr  = l & 15;
    const int lg  = l >> 4;
    const int wr  = w & 3;                  // row sub-tile (16 rows)
    const int cs  = w >> 2;                 // col sub-tile (16 cols)
    const int bid = blockIdx.x;
    const int swz = (bid & 7) * 128 + (bid >> 3);   // bijective XCD chunking
    const int b   = swz >> 5;               // batch
    const int r0  = (swz & 31) * RB;        // q-row base

    // ---- A fragments (rows r0+wr*16 .. +15), scale (log2e/8) folded, hi/lo
    constexpr float QS = 0.18033688011112042f;      // 0.125 * log2(e)
    bfrag ah0, al0, ah1, al1;
    {
        const float* qp = q + ((size_t)b * SQL + (size_t)(r0 + wr * 16 + lr)) * DD + lg * 8;
        const f32x4 x0 = *reinterpret_cast<const f32x4*>(qp);
        const f32x4 x1 = *reinterpret_cast<const f32x4*>(qp + 4);
        const f32x4 y0 = *reinterpret_cast<const f32x4*>(qp + 32);
        const f32x4 y1 = *reinterpret_cast<const f32x4*>(qp + 36);
        #pragma unroll
        for (int j = 0; j < 4; ++j) {
            float a = x0[j] * QS, c = x1[j] * QS;
            float d = y0[j] * QS, e = y1[j] * QS;
            unsigned short h;
            h = f2bf(a); ah0[j]     = (short)h; al0[j]     = (short)f2bf(a - bf2f(h));
            h = f2bf(c); ah0[j + 4] = (short)h; al0[j + 4] = (short)f2bf(c - bf2f(h));
            h = f2bf(d); ah1[j]     = (short)h; al1[j]     = (short)f2bf(d - bf2f(h));
            h = f2bf(e); ah1[j + 4] = (short)h; al1[j + 4] = (short)f2bf(e - bf2f(h));
        }
    }

    const unsigned char* ksrc = kswz + (size_t)b * SKL * 256;
    const float*         kraw = k + (size_t)b * SKL * DD;
    const int*           mth  = mask + ((size_t)b * SQL + r0 + (t >> 4)) * SKL + (t & 15) * 4;

    // LDS read byte-offsets for this lane's k fragments (swizzle-matched)
    const int colb   = cs * 16 + lr;                 // 0..63
    const int swb    = (colb & 7) << 4;
    const int kbase  = colb * 256;
    const int off_h0 = kbase + ((lg * 16) ^ swb);
    const int off_h1 = kbase + ((64 + lg * 16) ^ swb);
    const int off_l0 = kbase + 128 + ((lg * 16) ^ swb);
    const int off_l1 = kbase + 128 + ((64 + lg * 16) ^ swb);
    const int mrow0  = (wr * 16 + lg * 4) * 64 + colb;   // int index in mb

#define STAGE(C, KB, MB)                                                       \
    do {                                                                       \
        if constexpr (PRE) {                                                   \
            gld16(ksrc + (size_t)(C) * 16384 + t * 16, (KB) + t * 16);         \
        } else {                                                               \
            if (t < 512) {                                                     \
                const int _col = t >> 3, _g = t & 7;                           \
                const float* _kp = kraw + ((size_t)((C) * CK + _col)) * DD + _g * 8; \
                bfrag _h, _lo;                                                 \
                _Pragma("unroll")                                              \
                for (int _j = 0; _j < 8; ++_j) {                               \
                    const float _x = _kp[_j];                                  \
                    const unsigned short _hh = f2bf(_x);                       \
                    _h[_j]  = (short)_hh;                                      \
                    _lo[_j] = (short)f2bf(_x - bf2f(_hh));                     \
                }                                                              \
                const int _sw = (_col & 7) << 4;                               \
                *(bfrag*)((KB) + _col * 256 + ((_g * 16) ^ _sw))       = _h;   \
                *(bfrag*)((KB) + _col * 256 + 128 + ((_g * 16) ^ _sw)) = _lo;  \
            }                                                                  \
        }                                                                      \
        gld16(mth + (size_t)(C) * CK, (MB) + t * 16);                          \
    } while (0)

#define COMPUTE(C, KB, MB)                                                     \
    do {                                                                       \
        const unsigned* _mu = (const unsigned*)(MB);                           \
        unsigned _m[4];                                                        \
        _Pragma("unroll")                                                      \
        for (int _i = 0; _i < 4; ++_i) _m[_i] = _mu[mrow0 + _i * 64];          \
        const bfrag _bh0 = *(const bfrag*)((KB) + off_h0);                     \
        const bfrag _bh1 = *(const bfrag*)((KB) + off_h1);                     \
        const bfrag _bl0 = *(const bfrag*)((KB) + off_l0);                     \
        const bfrag _bl1 = *(const bfrag*)((KB) + off_l1);                     \
        f32x4 _a1 = {0.f, 0.f, 0.f, 0.f};                                      \
        f32x4 _a2 = {0.f, 0.f, 0.f, 0.f};                                      \
        f32x4 _a3 = {0.f, 0.f, 0.f, 0.f};                                      \
        _a1 = __builtin_amdgcn_mfma_f32_16x16x32_bf16(ah0, _bl0, _a1, 0, 0, 0);\
        _a2 = __builtin_amdgcn_mfma_f32_16x16x32_bf16(al0, _bh0, _a2, 0, 0, 0);\
        _a3 = __builtin_amdgcn_mfma_f32_16x16x32_bf16(ah0, _bh0, _a3, 0, 0, 0);\
        _a1 = __builtin_amdgcn_mfma_f32_16x16x32_bf16(ah1, _bl1, _a1, 0, 0, 0);\
        _a2 = __builtin_amdgcn_mfma_f32_16x16x32_bf16(al1, _bh1, _a2, 0, 0, 0);\
        _a3 = __builtin_amdgcn_mfma_f32_16x16x32_bf16(ah1, _bh1, _a3, 0, 0, 0);\
        const f32x4 _s = (_a1 + _a2) + _a3;                                    \
        float _e[4];                                                           \
        _Pragma("unroll")                                                      \
        for (int _i = 0; _i < 4; ++_i) {                                       \
            const float _v = _m[_i] ? exp2f(_s[_i]) : 0.f;                     \
            _e[_i] = _v;                                                       \
            psum[_i] += _v;                                                    \
        }                                                                      \
        sc[2 * (C)    ] = (unsigned)f2bf(_e[0]) | ((unsigned)f2bf(_e[1]) << 16);\
        sc[2 * (C) + 1] = (unsigned)f2bf(_e[2]) | ((unsigned)f2bf(_e[3]) << 16);\
    } while (0)

    unsigned sc[NC * 2];              // packed bf16 exp values (64 VGPR)
    float psum[4] = {0.f, 0.f, 0.f, 0.f};

    STAGE(0, kb0, mb0);
    __syncthreads();

    #pragma unroll
    for (int p = 0; p < NC / 2; ++p) {
        STAGE(2 * p + 1, kb1, mb1);
        COMPUTE(2 * p, kb0, mb0);
        __syncthreads();
        if (2 * p + 2 < NC) STAGE(2 * p + 2, kb0, mb0);
        COMPUTE(2 * p + 1, kb1, mb1);
        __syncthreads();
    }
#undef COMPUTE
#undef STAGE

    // ---- row sums: shfl within 16-lane col groups, LDS across 4 col-waves
    #pragma unroll
    for (int i = 0; i < 4; ++i) {
        float s = psum[i];
        s += __shfl_xor(s, 1, 64);
        s += __shfl_xor(s, 2, 64);
        s += __shfl_xor(s, 4, 64);
        s += __shfl_xor(s, 8, 64);
        psum[i] = s;
    }
    if (lr == 0) {
        #pragma unroll
        for (int i = 0; i < 4; ++i)
            s_red[w * 16 + lg * 4 + i] = psum[i];
    }
    __syncthreads();

    float rinv[4];
    #pragma unroll
    for (int i = 0; i < 4; ++i) {
        float tot = 0.f;
        #pragma unroll
        for (int c4 = 0; c4 < 4; ++c4)
            tot += s_red[(wr + 4 * c4) * 16 + lg * 4 + i];
        rinv[i] = 1.0f / tot;
    }

    // ---- unpack, normalize, store
    float* orow[4];
    #pragma unroll
    for (int i = 0; i < 4; ++i)
        orow[i] = out + ((size_t)b * SQL + (size_t)(r0 + wr * 16 + lg * 4 + i)) * SKL
                      + cs * 16 + lr;
    #pragma unroll
    for (int c = 0; c < NC; ++c) {
        const unsigned p01 = sc[2 * c];
        const unsigned p23 = sc[2 * c + 1];
        orow[0][c * CK] = bf2f((unsigned short)(p01 & 0xffffu)) * rinv[0];
        orow[1][c * CK] = bf2f((unsigned short)(p01 >> 16))     * rinv[1];
        orow[2][c * CK] = bf2f((unsigned short)(p23 & 0xffffu)) * rinv[2];
        orow[3][c * CK] = bf2f((unsigned short)(p23 >> 16))     * rinv[3];
    }
}

extern "C" void kernel_launch(void* const* d_in, const int* in_sizes, int n_in,
                              void* d_out, int out_size, void* d_ws, size_t ws_size,
                              hipStream_t stream) {
    const float* q    = (const float*)d_in[0];
    const float* k    = (const float*)d_in[1];
    const int*   mask = (const int*)d_in[2];
    float*       out  = (float*)d_out;

    const size_t NEED = (size_t)BB * SKL * 256;   // 16.78 MB swizzled k planes

    if (ws_size >= NEED) {
        split_k_swz<<<2048, 256, 0, stream>>>(k, (unsigned char*)d_ws);
        sdpa_big<true><<<1024, 1024, 0, stream>>>(q, k, mask,
                                                  (const unsigned char*)d_ws, out);
    } else {
        sdpa_big<false><<<1024, 1024, 0, stream>>>(q, k, mask, nullptr, out);
    }
}

// Round 8
// 468.149 us; speedup vs baseline: 1.0666x; 1.0666x over previous
//
#include <hip/hip_runtime.h>
#include <math.h>

constexpr int BB  = 32;
constexpr int SQL = 2048;
constexpr int SKL = 2048;
constexpr int DD  = 64;
constexpr int NTW = 16;           // tiles per wave (wave owns 256 cols)

using f32x4 = __attribute__((ext_vector_type(4))) float;
using bfrag = __attribute__((ext_vector_type(8))) short;   // 8 bf16 = 4 VGPR
using us4   = __attribute__((ext_vector_type(4))) unsigned short;
typedef unsigned long long u64;

static __device__ __forceinline__ unsigned short f2bf(float x) {
    unsigned u = __float_as_uint(x);
    u = u + 0x7FFFu + ((u >> 16) & 1u);          // round-nearest-even
    return (unsigned short)(u >> 16);
}
static __device__ __forceinline__ float bf2f(unsigned short h) {
    return __uint_as_float((unsigned)h << 16);
}

// ---- prepass 1: mask int32 -> 1 bit/elem, natural col order.
// Thread g owns ints [8g, 8g+8) -> byte g. All 8 int4 loads issued before
// use (deep MLP); byte stores are lane-consecutive (coalesced).
__global__ __launch_bounds__(256) void compress_mask(
    const int* __restrict__ m, unsigned char* __restrict__ bm)
{
    const int t = threadIdx.x;
    const size_t base = (size_t)blockIdx.x * 1024;   // byte index base
    const size_t g0 = base + t;
    const int4* mp = (const int4*)m;
    int4 a0 = mp[(g0)       * 2], a1 = mp[(g0)       * 2 + 1];
    int4 b0 = mp[(g0 + 256) * 2], b1 = mp[(g0 + 256) * 2 + 1];
    int4 c0 = mp[(g0 + 512) * 2], c1 = mp[(g0 + 512) * 2 + 1];
    int4 d0 = mp[(g0 + 768) * 2], d1 = mp[(g0 + 768) * 2 + 1];
#define PACK8(v0, v1)                                                         \
    (unsigned char)((v0.x != 0 ? 1u : 0u)  | (v0.y != 0 ? 2u : 0u)   |        \
                    (v0.z != 0 ? 4u : 0u)  | (v0.w != 0 ? 8u : 0u)   |        \
                    (v1.x != 0 ? 16u : 0u) | (v1.y != 0 ? 32u : 0u)  |        \
                    (v1.z != 0 ? 64u : 0u) | (v1.w != 0 ? 128u : 0u))
    bm[g0]       = PACK8(a0, a1);
    bm[g0 + 256] = PACK8(b0, b1);
    bm[g0 + 512] = PACK8(c0, c1);
    bm[g0 + 768] = PACK8(d0, d1);
#undef PACK8
}

// ---- prepass 2: k fp32 -> bf16 hi/lo planes (same [B][SK][D] layout)
__global__ __launch_bounds__(256) void split_k(
    const float* __restrict__ k, unsigned short* __restrict__ kh,
    unsigned short* __restrict__ kl, int n4)
{
    int i0 = blockIdx.x * blockDim.x + threadIdx.x;
    int stride = gridDim.x * blockDim.x;
    for (int i = i0; i < n4; i += stride) {
        f32x4 x = reinterpret_cast<const f32x4*>(k)[i];
        us4 h, lo;
        #pragma unroll
        for (int j = 0; j < 4; ++j) {
            unsigned short hh = f2bf(x[j]);
            h[j]  = hh;
            lo[j] = f2bf(x[j] - bf2f(hh));
        }
        reinterpret_cast<us4*>(kh)[i] = h;
        reinterpret_cast<us4*>(kl)[i] = lo;
    }
}

struct KS { bfrag h0, h1, l0, l1; };

// ---- main. Swapped MFMA: C = K_tile x Q  ->  lane l holds q-row (l&15),
// k-cols (l>>4)*4+{0..3}  ->  float4 stores, 4 adjacent mask bits.
// MODE: 2 = bitmask + kh/kl planes, 1 = bitmask + raw k, 0 = all raw.
template<int MODE>
__global__ __launch_bounds__(512, 4) void sdpa_v8(
    const float* __restrict__ q, const float* __restrict__ k,
    const int* __restrict__ mask, const unsigned char* __restrict__ bm,
    const unsigned short* __restrict__ kh, const unsigned short* __restrict__ kl,
    float* __restrict__ out)
{
    __shared__ float s_red[8][16];

    const int t   = threadIdx.x;
    const int l   = t & 63;
    const int w   = t >> 6;
    const int lr  = l & 15;
    const int lg  = l >> 4;
    const int bid = blockIdx.x;
    const int swz = (bid & 7) * 512 + (bid >> 3);   // bijective XCD chunking
    const int b   = swz >> 7;                       // batch
    const int r0  = (swz & 127) * 16;               // q-row base
    const int c0  = w * 256;                        // wave's col base
    const size_t rowg = (size_t)b * SQL + (size_t)(r0 + lr);  // lane's q-row

    // ---- q fragments (B operand), scale (log2e/8) folded, hi/lo split
    constexpr float QS = 0.18033688011112042f;      // 0.125 * log2(e)
    bfrag qh0, ql0, qh1, ql1;
    {
        const float* qp = q + rowg * DD + lg * 8;
        const f32x4 x0 = *reinterpret_cast<const f32x4*>(qp);
        const f32x4 x1 = *reinterpret_cast<const f32x4*>(qp + 4);
        const f32x4 y0 = *reinterpret_cast<const f32x4*>(qp + 32);
        const f32x4 y1 = *reinterpret_cast<const f32x4*>(qp + 36);
        #pragma unroll
        for (int j = 0; j < 4; ++j) {
            float a = x0[j] * QS, c = x1[j] * QS;
            float d = y0[j] * QS, e = y1[j] * QS;
            unsigned short h;
            h = f2bf(a); qh0[j]     = (short)h; ql0[j]     = (short)f2bf(a - bf2f(h));
            h = f2bf(c); qh0[j + 4] = (short)h; ql0[j + 4] = (short)f2bf(c - bf2f(h));
            h = f2bf(d); qh1[j]     = (short)h; ql1[j]     = (short)f2bf(d - bf2f(h));
            h = f2bf(e); qh1[j + 4] = (short)h; ql1[j + 4] = (short)f2bf(e - bf2f(h));
        }
    }

    // ---- mask bits for this lane's row, this wave's 256 cols (32 B, once)
    u64 mw0 = 0, mw1 = 0, mw2 = 0, mw3 = 0;
    if constexpr (MODE >= 1) {
        const ulonglong2* wp =
            (const ulonglong2*)(bm + rowg * (SKL / 8) + w * 32);
        const ulonglong2 v01 = wp[0];
        const ulonglong2 v23 = wp[1];
        mw0 = v01.x; mw1 = v01.y; mw2 = v23.x; mw3 = v23.y;
    }

    // ---- k pointers (A operand): row of A = k-col = c0 + T*16 + lr
    const unsigned short* khp = (MODE == 2)
        ? kh + ((size_t)b * SKL + c0 + lr) * DD + lg * 8 : nullptr;
    const unsigned short* klp = (MODE == 2)
        ? kl + ((size_t)b * SKL + c0 + lr) * DD + lg * 8 : nullptr;
    const float* krp = (MODE != 2)
        ? k + ((size_t)b * SKL + c0 + lr) * DD + lg * 8 : nullptr;
    const int* mrp = (MODE == 0)
        ? mask + rowg * SKL + c0 + lg * 4 : nullptr;

#define LOADK(T, BUF)                                                          \
    do {                                                                       \
        if constexpr (MODE == 2) {                                             \
            const unsigned short* _ph = khp + (size_t)(T) * (16 * DD);         \
            const unsigned short* _pl = klp + (size_t)(T) * (16 * DD);         \
            BUF.h0 = *(const bfrag*)_ph;  BUF.h1 = *(const bfrag*)(_ph + 32);  \
            BUF.l0 = *(const bfrag*)_pl;  BUF.l1 = *(const bfrag*)(_pl + 32);  \
        } else {                                                               \
            const float* _kp = krp + (size_t)(T) * (16 * DD);                  \
            const f32x4 _x0 = *(const f32x4*)_kp;                              \
            const f32x4 _x1 = *(const f32x4*)(_kp + 4);                        \
            const f32x4 _y0 = *(const f32x4*)(_kp + 32);                       \
            const f32x4 _y1 = *(const f32x4*)(_kp + 36);                       \
            _Pragma("unroll")                                                  \
            for (int _j = 0; _j < 4; ++_j) {                                   \
                unsigned short _h;                                             \
                _h = f2bf(_x0[_j]); BUF.h0[_j]   = (short)_h;                  \
                BUF.l0[_j]   = (short)f2bf(_x0[_j] - bf2f(_h));                \
                _h = f2bf(_x1[_j]); BUF.h0[_j+4] = (short)_h;                  \
                BUF.l0[_j+4] = (short)f2bf(_x1[_j] - bf2f(_h));                \
                _h = f2bf(_y0[_j]); BUF.h1[_j]   = (short)_h;                  \
                BUF.l1[_j]   = (short)f2bf(_y0[_j] - bf2f(_h));                \
                _h = f2bf(_y1[_j]); BUF.h1[_j+4] = (short)_h;                  \
                BUF.l1[_j+4] = (short)f2bf(_y1[_j] - bf2f(_h));                \
            }                                                                  \
        }                                                                      \
    } while (0)

#define PHASE(T, KC, KN, MW)                                                   \
    do {                                                                       \
        LOADK(((T) + 1 > NTW - 1 ? NTW - 1 : (T) + 1), KN);                    \
        int4 _mv;                                                              \
        if constexpr (MODE == 0) _mv = *(const int4*)(mrp + (T) * 16);         \
        f32x4 _a1 = {0.f, 0.f, 0.f, 0.f};                                      \
        f32x4 _a2 = {0.f, 0.f, 0.f, 0.f};                                      \
        f32x4 _a3 = {0.f, 0.f, 0.f, 0.f};                                      \
        _a1 = __builtin_amdgcn_mfma_f32_16x16x32_bf16(KC.l0, qh0, _a1, 0, 0, 0);\
        _a2 = __builtin_amdgcn_mfma_f32_16x16x32_bf16(KC.h0, ql0, _a2, 0, 0, 0);\
        _a3 = __builtin_amdgcn_mfma_f32_16x16x32_bf16(KC.h0, qh0, _a3, 0, 0, 0);\
        _a1 = __builtin_amdgcn_mfma_f32_16x16x32_bf16(KC.l1, qh1, _a1, 0, 0, 0);\
        _a2 = __builtin_amdgcn_mfma_f32_16x16x32_bf16(KC.h1, ql1, _a2, 0, 0, 0);\
        _a3 = __builtin_amdgcn_mfma_f32_16x16x32_bf16(KC.h1, qh1, _a3, 0, 0, 0);\
        const f32x4 _s = (_a1 + _a2) + _a3;                                    \
        unsigned _nib;                                                         \
        if constexpr (MODE >= 1)                                               \
            _nib = (unsigned)((MW) >> (((T) & 3) * 16 + lg * 4)) & 0xFu;       \
        else                                                                   \
            _nib = (_mv.x != 0 ? 1u : 0u) | (_mv.y != 0 ? 2u : 0u)             \
                 | (_mv.z != 0 ? 4u : 0u) | (_mv.w != 0 ? 8u : 0u);            \
        const float _e0 = (_nib & 1u) ? exp2f(_s[0]) : 0.f;                    \
        const float _e1 = (_nib & 2u) ? exp2f(_s[1]) : 0.f;                    \
        const float _e2 = (_nib & 4u) ? exp2f(_s[2]) : 0.f;                    \
        const float _e3 = (_nib & 8u) ? exp2f(_s[3]) : 0.f;                    \
        psum += (_e0 + _e1) + (_e2 + _e3);                                     \
        sc[2 * (T)    ] = (unsigned)f2bf(_e0) | ((unsigned)f2bf(_e1) << 16);   \
        sc[2 * (T) + 1] = (unsigned)f2bf(_e2) | ((unsigned)f2bf(_e3) << 16);   \
    } while (0)

    unsigned sc[2 * NTW];             // packed bf16 exp values (32 VGPR)
    float psum = 0.f;

    KS kA, kB;
    LOADK(0, kA);

    PHASE(0,  kA, kB, mw0); PHASE(1,  kB, kA, mw0);
    PHASE(2,  kA, kB, mw0); PHASE(3,  kB, kA, mw0);
    PHASE(4,  kA, kB, mw1); PHASE(5,  kB, kA, mw1);
    PHASE(6,  kA, kB, mw1); PHASE(7,  kB, kA, mw1);
    PHASE(8,  kA, kB, mw2); PHASE(9,  kB, kA, mw2);
    PHASE(10, kA, kB, mw2); PHASE(11, kB, kA, mw2);
    PHASE(12, kA, kB, mw3); PHASE(13, kB, kA, mw3);
    PHASE(14, kA, kB, mw3); PHASE(15, kB, kA, mw3);
#undef PHASE
#undef LOADK

    // ---- row sums: lanes {l, l^16, l^32, l^48} share a row
    float s = psum;
    s += __shfl_xor(s, 16, 64);
    s += __shfl_xor(s, 32, 64);
    if (l < 16) s_red[w][lr] = s;
    __syncthreads();

    float tot = 0.f;
    #pragma unroll
    for (int ww = 0; ww < 8; ++ww)
        tot += s_red[ww][lr];
    const float rinv = 1.0f / tot;

    // ---- unpack, normalize, float4 store
    float* op = out + rowg * SKL + c0 + lg * 4;
    #pragma unroll
    for (int T = 0; T < NTW; ++T) {
        const unsigned p01 = sc[2 * T];
        const unsigned p23 = sc[2 * T + 1];
        f32x4 o;
        o[0] = bf2f((unsigned short)(p01 & 0xffffu)) * rinv;
        o[1] = bf2f((unsigned short)(p01 >> 16))     * rinv;
        o[2] = bf2f((unsigned short)(p23 & 0xffffu)) * rinv;
        o[3] = bf2f((unsigned short)(p23 >> 16))     * rinv;
        *reinterpret_cast<f32x4*>(op + T * 16) = o;
    }
}

extern "C" void kernel_launch(void* const* d_in, const int* in_sizes, int n_in,
                              void* d_out, int out_size, void* d_ws, size_t ws_size,
                              hipStream_t stream) {
    const float* q    = (const float*)d_in[0];
    const float* k    = (const float*)d_in[1];
    const int*   mask = (const int*)d_in[2];
    float*       out  = (float*)d_out;

    const size_t BM_B = (size_t)BB * SQL * SKL / 8;     // 16.78 MB bitmask
    const size_t KE   = (size_t)BB * SKL * DD;          // 4.19M elems
    const size_t KP_B = KE * 4;                         // kh+kl bf16 = 33.55 MB

    dim3 grid(4096);    // XCD-swizzled in-kernel; 8 waves each

    if (ws_size >= BM_B + KP_B) {
        unsigned char*  bmp = (unsigned char*)d_ws;
        unsigned short* khp = (unsigned short*)((char*)d_ws + BM_B);
        unsigned short* klp = khp + KE;
        compress_mask<<<16384, 256, 0, stream>>>(mask, bmp);
        split_k<<<1024, 256, 0, stream>>>(k, khp, klp, (int)(KE / 4));
        sdpa_v8<2><<<grid, 512, 0, stream>>>(q, k, mask, bmp, khp, klp, out);
    } else if (ws_size >= BM_B) {
        unsigned char* bmp = (unsigned char*)d_ws;
        compress_mask<<<16384, 256, 0, stream>>>(mask, bmp);
        sdpa_v8<1><<<grid, 512, 0, stream>>>(q, k, mask, bmp, nullptr, nullptr, out);
    } else {
        sdpa_v8<0><<<grid, 512, 0, stream>>>(q, k, mask, nullptr, nullptr, nullptr, out);
    }
}

// Round 9
// 344.032 us; speedup vs baseline: 1.4515x; 1.3608x over previous
//
#include <hip/hip_runtime.h>
#include <math.h>

constexpr int BB  = 32;
constexpr int SQL = 2048;
constexpr int SKL = 2048;
constexpr int DD  = 64;

using f32x4 = __attribute__((ext_vector_type(4))) float;
using bfrag = __attribute__((ext_vector_type(8))) short;   // 8 bf16 = 4 VGPR
typedef unsigned long long u64;

static __device__ __forceinline__ unsigned short f2bf(float x) {
    unsigned u = __float_as_uint(x);
    u = u + 0x7FFFu + ((u >> 16) & 1u);          // round-nearest-even
    return (unsigned short)(u >> 16);
}
static __device__ __forceinline__ float bf2f(unsigned short h) {
    return __uint_as_float((unsigned)h << 16);
}

// async global->LDS, 16 B per lane (wave-uniform base + lane*16 dest)
static __device__ __forceinline__ void gld16(const void* g, void* l) {
    __builtin_amdgcn_global_load_lds(
        (const __attribute__((address_space(1))) void*)(size_t)g,
        (__attribute__((address_space(3))) void*)(unsigned)(size_t)l,
        16, 0, 0);
}

// ---- prepass 1: mask int32 -> 1 bit/elem, natural col order (proven r8)
__global__ __launch_bounds__(256) void compress_mask(
    const int* __restrict__ m, unsigned char* __restrict__ bm)
{
    const int t = threadIdx.x;
    const size_t g0 = (size_t)blockIdx.x * 1024 + t;
    const int4* mp = (const int4*)m;
    int4 a0 = mp[(g0)       * 2], a1 = mp[(g0)       * 2 + 1];
    int4 b0 = mp[(g0 + 256) * 2], b1 = mp[(g0 + 256) * 2 + 1];
    int4 c0 = mp[(g0 + 512) * 2], c1 = mp[(g0 + 512) * 2 + 1];
    int4 d0 = mp[(g0 + 768) * 2], d1 = mp[(g0 + 768) * 2 + 1];
#define PACK8(v0, v1)                                                         \
    (unsigned char)((v0.x != 0 ? 1u : 0u)  | (v0.y != 0 ? 2u : 0u)   |        \
                    (v0.z != 0 ? 4u : 0u)  | (v0.w != 0 ? 8u : 0u)   |        \
                    (v1.x != 0 ? 16u : 0u) | (v1.y != 0 ? 32u : 0u)  |        \
                    (v1.z != 0 ? 64u : 0u) | (v1.w != 0 ? 128u : 0u))
    bm[g0]       = PACK8(a0, a1);
    bm[g0 + 256] = PACK8(b0, b1);
    bm[g0 + 512] = PACK8(c0, c1);
    bm[g0 + 768] = PACK8(d0, d1);
#undef PACK8
}

// ---- prepass 2: k fp32 -> swizzled bf16 hi/lo records (proven r6).
// Per (b,c): 256 B = [hi 128B][lo 128B]; 16-B groups XOR'd by ((c&7)<<4).
__global__ __launch_bounds__(256) void split_k_swz(
    const float* __restrict__ k, unsigned char* __restrict__ kswz)
{
    const int i0 = blockIdx.x * blockDim.x + threadIdx.x;  // (b,c,g)
    const int g  = i0 & 7;
    const int c  = (i0 >> 3) & 2047;
    const int b  = i0 >> 14;
    const float* kp = k + ((size_t)(b * 2048 + c)) * DD + g * 8;
    bfrag h, lo;
    #pragma unroll
    for (int j = 0; j < 8; ++j) {
        const float x = kp[j];
        const unsigned short hh = f2bf(x);
        h[j]  = (short)hh;
        lo[j] = (short)f2bf(x - bf2f(hh));
    }
    const int sw = (c & 7) << 4;
    unsigned char* rec = kswz + ((size_t)(b * 2048 + c)) * 256;
    *(bfrag*)(rec + ((g * 16) ^ sw))       = h;
    *(bfrag*)(rec + 128 + ((g * 16) ^ sw)) = lo;
}

// ---- main: block = 8 waves = 16 q-rows x 2048 cols; wave w owns 256 cols.
// k fed via per-wave LDS double buffer filled by global_load_lds DMA,
// counted vmcnt(4) (one tile always in flight), no barriers in the loop.
template<bool PRE>
__global__ __launch_bounds__(512, 4) void sdpa_v9(
    const float* __restrict__ q, const float* __restrict__ k,
    const int* __restrict__ mask, const unsigned char* __restrict__ bm,
    const unsigned char* __restrict__ kswz, float* __restrict__ out)
{
    __shared__ char klds[8][2][4096];      // [wave][buf][16 cols x 256B]
    __shared__ float s_red[8][16];

    const int t   = threadIdx.x;
    const int l   = t & 63;
    const int w   = t >> 6;
    const int lr  = l & 15;
    const int lg  = l >> 4;
    const int bid = blockIdx.x;
    const int swz = (bid & 7) * 512 + (bid >> 3);   // bijective XCD chunking
    const int b   = swz >> 7;                       // batch
    const int r0  = (swz & 127) * 16;               // q-row base
    const int c0  = w * 256;                        // wave's col base
    const size_t rowg = (size_t)b * SQL + (size_t)(r0 + lr);  // lane's q-row
    const int swk = (lr & 7) << 4;                  // LDS swizzle key

    // ---- q fragments (B operand), scale (log2e/8) folded, hi/lo split
    constexpr float QS = 0.18033688011112042f;      // 0.125 * log2(e)
    bfrag qh0, ql0, qh1, ql1;
    {
        const float* qp = q + rowg * DD + lg * 8;
        const f32x4 x0 = *reinterpret_cast<const f32x4*>(qp);
        const f32x4 x1 = *reinterpret_cast<const f32x4*>(qp + 4);
        const f32x4 y0 = *reinterpret_cast<const f32x4*>(qp + 32);
        const f32x4 y1 = *reinterpret_cast<const f32x4*>(qp + 36);
        #pragma unroll
        for (int j = 0; j < 4; ++j) {
            float a = x0[j] * QS, c = x1[j] * QS;
            float d = y0[j] * QS, e = y1[j] * QS;
            unsigned short h;
            h = f2bf(a); qh0[j]     = (short)h; ql0[j]     = (short)f2bf(a - bf2f(h));
            h = f2bf(c); qh0[j + 4] = (short)h; ql0[j + 4] = (short)f2bf(c - bf2f(h));
            h = f2bf(d); qh1[j]     = (short)h; ql1[j]     = (short)f2bf(d - bf2f(h));
            h = f2bf(e); qh1[j + 4] = (short)h; ql1[j + 4] = (short)f2bf(e - bf2f(h));
        }
    }

    // ---- mask bits for this lane's row, this wave's 256 cols (32 B, once)
    u64 mw0 = 0, mw1 = 0, mw2 = 0, mw3 = 0;
    if constexpr (PRE) {
        const ulonglong2* wp =
            (const ulonglong2*)(bm + rowg * (SKL / 8) + w * 32);
        const ulonglong2 v01 = wp[0];
        const ulonglong2 v23 = wp[1];
        mw0 = v01.x; mw1 = v01.y; mw2 = v23.x; mw3 = v23.y;
    }

    const char*  ksrc = PRE ? (const char*)(kswz + (size_t)b * SKL * 256) : nullptr;
    const float* kraw = PRE ? nullptr : k + (size_t)b * SKL * DD;
    const int*   mrp  = PRE ? nullptr : mask + rowg * SKL + c0 + lg * 4;
    char* seg = &klds[w][0][0];

#define STAGE(T)                                                               \
    do {                                                                       \
        char* _d = seg + (((T) & 1) << 12);                                    \
        if constexpr (PRE) {                                                   \
            const char* _s = ksrc + (size_t)(c0 + (T) * 16) * 256;             \
            gld16(_s + l * 16,        _d + l * 16);                            \
            gld16(_s + 1024 + l * 16, _d + 1024 + l * 16);                     \
            gld16(_s + 2048 + l * 16, _d + 2048 + l * 16);                     \
            gld16(_s + 3072 + l * 16, _d + 3072 + l * 16);                     \
        } else {                                                               \
            const float* _kc = kraw + (size_t)(c0 + (T) * 16 + lr) * DD;       \
            const f32x4 _a0 = *(const f32x4*)(_kc + lg * 8);                   \
            const f32x4 _a1 = *(const f32x4*)(_kc + lg * 8 + 4);               \
            const f32x4 _b0 = *(const f32x4*)(_kc + (lg + 4) * 8);             \
            const f32x4 _b1 = *(const f32x4*)(_kc + (lg + 4) * 8 + 4);         \
            bfrag _h, _o;                                                      \
            _Pragma("unroll")                                                  \
            for (int _j = 0; _j < 4; ++_j) {                                   \
                unsigned short _t;                                             \
                _t = f2bf(_a0[_j]); _h[_j]   = (short)_t;                      \
                _o[_j]   = (short)f2bf(_a0[_j] - bf2f(_t));                    \
                _t = f2bf(_a1[_j]); _h[_j+4] = (short)_t;                      \
                _o[_j+4] = (short)f2bf(_a1[_j] - bf2f(_t));                    \
            }                                                                  \
            char* _rec = _d + lr * 256;                                        \
            *(bfrag*)(_rec + ((lg * 16) ^ swk))       = _h;                    \
            *(bfrag*)(_rec + 128 + ((lg * 16) ^ swk)) = _o;                    \
            _Pragma("unroll")                                                  \
            for (int _j = 0; _j < 4; ++_j) {                                   \
                unsigned short _t;                                             \
                _t = f2bf(_b0[_j]); _h[_j]   = (short)_t;                      \
                _o[_j]   = (short)f2bf(_b0[_j] - bf2f(_t));                    \
                _t = f2bf(_b1[_j]); _h[_j+4] = (short)_t;                      \
                _o[_j+4] = (short)f2bf(_b1[_j] - bf2f(_t));                    \
            }                                                                  \
            *(bfrag*)(_rec + (((lg + 4) * 16) ^ swk))       = _h;              \
            *(bfrag*)(_rec + 128 + (((lg + 4) * 16) ^ swk)) = _o;              \
        }                                                                      \
    } while (0)

#define ITER(T, VMC, MW)                                                       \
    do {                                                                       \
        if constexpr (PRE)                                                     \
            asm volatile("s_waitcnt vmcnt(" #VMC ")" ::: "memory");            \
        const char* _c = seg + (((T) & 1) << 12) + lr * 256;                   \
        const bfrag _kh0 = *(const bfrag*)(_c + ((lg * 16) ^ swk));            \
        const bfrag _kh1 = *(const bfrag*)(_c + (((lg + 4) * 16) ^ swk));      \
        const bfrag _kl0 = *(const bfrag*)(_c + 128 + ((lg * 16) ^ swk));      \
        const bfrag _kl1 = *(const bfrag*)(_c + 128 + (((lg + 4) * 16) ^ swk));\
        asm volatile("s_waitcnt lgkmcnt(0)" ::: "memory");                     \
        __builtin_amdgcn_sched_barrier(0);                                     \
        if constexpr ((T) + 2 < 16) STAGE((T) + 2);                            \
        int4 _mv;                                                              \
        if constexpr (!PRE) _mv = *(const int4*)(mrp + (T) * 16);              \
        f32x4 _a1 = {0.f, 0.f, 0.f, 0.f};                                      \
        f32x4 _a2 = {0.f, 0.f, 0.f, 0.f};                                      \
        f32x4 _a3 = {0.f, 0.f, 0.f, 0.f};                                      \
        _a1 = __builtin_amdgcn_mfma_f32_16x16x32_bf16(_kl0, qh0, _a1, 0, 0, 0);\
        _a2 = __builtin_amdgcn_mfma_f32_16x16x32_bf16(_kh0, ql0, _a2, 0, 0, 0);\
        _a3 = __builtin_amdgcn_mfma_f32_16x16x32_bf16(_kh0, qh0, _a3, 0, 0, 0);\
        _a1 = __builtin_amdgcn_mfma_f32_16x16x32_bf16(_kl1, qh1, _a1, 0, 0, 0);\
        _a2 = __builtin_amdgcn_mfma_f32_16x16x32_bf16(_kh1, ql1, _a2, 0, 0, 0);\
        _a3 = __builtin_amdgcn_mfma_f32_16x16x32_bf16(_kh1, qh1, _a3, 0, 0, 0);\
        const f32x4 _s = (_a1 + _a2) + _a3;                                    \
        unsigned _nib;                                                         \
        if constexpr (PRE)                                                     \
            _nib = (unsigned)((MW) >> (((T) & 3) * 16 + lg * 4)) & 0xFu;       \
        else                                                                   \
            _nib = (_mv.x != 0 ? 1u : 0u) | (_mv.y != 0 ? 2u : 0u)             \
                 | (_mv.z != 0 ? 4u : 0u) | (_mv.w != 0 ? 8u : 0u);            \
        const float _e0 = (_nib & 1u) ? exp2f(_s[0]) : 0.f;                    \
        const float _e1 = (_nib & 2u) ? exp2f(_s[1]) : 0.f;                    \
        const float _e2 = (_nib & 4u) ? exp2f(_s[2]) : 0.f;                    \
        const float _e3 = (_nib & 8u) ? exp2f(_s[3]) : 0.f;                    \
        psum += (_e0 + _e1) + (_e2 + _e3);                                     \
        sc[2 * (T)    ] = (unsigned)f2bf(_e0) | ((unsigned)f2bf(_e1) << 16);   \
        sc[2 * (T) + 1] = (unsigned)f2bf(_e2) | ((unsigned)f2bf(_e3) << 16);   \
    } while (0)

    unsigned sc[32];                  // packed bf16 exp values (32 VGPR)
    float psum = 0.f;

    STAGE(0);
    STAGE(1);

    ITER(0,  4, mw0); ITER(1,  4, mw0); ITER(2,  4, mw0); ITER(3,  4, mw0);
    ITER(4,  4, mw1); ITER(5,  4, mw1); ITER(6,  4, mw1); ITER(7,  4, mw1);
    ITER(8,  4, mw2); ITER(9,  4, mw2); ITER(10, 4, mw2); ITER(11, 4, mw2);
    ITER(12, 4, mw3); ITER(13, 4, mw3); ITER(14, 4, mw3); ITER(15, 0, mw3);
#undef ITER
#undef STAGE

    // ---- row sums: lanes {l, l^16, l^32, l^48} share a row
    float s = psum;
    s += __shfl_xor(s, 16, 64);
    s += __shfl_xor(s, 32, 64);
    if (l < 16) s_red[w][lr] = s;
    __syncthreads();

    float tot = 0.f;
    #pragma unroll
    for (int ww = 0; ww < 8; ++ww)
        tot += s_red[ww][lr];
    const float rinv = 1.0f / tot;

    // ---- unpack, normalize, float4 store
    float* op = out + rowg * SKL + c0 + lg * 4;
    #pragma unroll
    for (int T = 0; T < 16; ++T) {
        const unsigned p01 = sc[2 * T];
        const unsigned p23 = sc[2 * T + 1];
        f32x4 o;
        o[0] = bf2f((unsigned short)(p01 & 0xffffu)) * rinv;
        o[1] = bf2f((unsigned short)(p01 >> 16))     * rinv;
        o[2] = bf2f((unsigned short)(p23 & 0xffffu)) * rinv;
        o[3] = bf2f((unsigned short)(p23 >> 16))     * rinv;
        *reinterpret_cast<f32x4*>(op + T * 16) = o;
    }
}

extern "C" void kernel_launch(void* const* d_in, const int* in_sizes, int n_in,
                              void* d_out, int out_size, void* d_ws, size_t ws_size,
                              hipStream_t stream) {
    const float* q    = (const float*)d_in[0];
    const float* k    = (const float*)d_in[1];
    const int*   mask = (const int*)d_in[2];
    float*       out  = (float*)d_out;

    const size_t BM_B = (size_t)BB * SQL * SKL / 8;   // 16.78 MB bitmask
    const size_t KS_B = (size_t)BB * SKL * 256;       // 16.78 MB swizzled k

    dim3 grid(4096);    // XCD-swizzled in-kernel; 8 waves each

    if (ws_size >= BM_B + KS_B) {
        unsigned char* bmp = (unsigned char*)d_ws;
        unsigned char* ksp = (unsigned char*)d_ws + BM_B;
        compress_mask<<<16384, 256, 0, stream>>>(mask, bmp);
        split_k_swz<<<2048, 256, 0, stream>>>(k, ksp);
        sdpa_v9<true><<<grid, 512, 0, stream>>>(q, k, mask, bmp, ksp, out);
    } else {
        sdpa_v9<false><<<grid, 512, 0, stream>>>(q, k, mask, nullptr, nullptr, out);
    }
}